// Round 1
// baseline (125.980 us; speedup 1.0000x reference)
//
#include <hip/hip_runtime.h>

#define CIN   128
#define HH    224
#define WW    224
#define COUT  256
#define HO    222
#define WO    222
#define PLANE (224 * 224 * 64)   // one channel-half plane of packed x, in elems

typedef unsigned short u16;
typedef unsigned int   u32;
typedef __bf16  bf16x8 __attribute__((ext_vector_type(8)));
typedef float   f32x4  __attribute__((ext_vector_type(4)));

__device__ __forceinline__ u16 f2bf(float f) {
  union { float f; u32 u; } v; v.f = f;
  u32 u = v.u;
  return (u16)((u + 0x7FFFu + ((u >> 16) & 1u)) >> 16);  // RNE
}

// ---------------- pre-pass 1: pack weights ----------------
// Wp layout: [mt(2)][khw(9)][ch(2)][mr(128)][jc'(8)][e(8)]  bf16
// block jc' holds source c-block jc = jc' ^ (mr&7)   (bank-conflict swizzle)
__global__ void pack_w(const float* __restrict__ w, u16* __restrict__ wp) {
  int b   = blockIdx.x * 256 + threadIdx.x;     // 0..36863 (16B blocks)
  int jcp = b & 7;
  int r1  = b >> 3;
  int mr  = r1 & 127;
  int r2  = r1 >> 7;
  int ch  = r2 & 1;
  int r3  = r2 >> 1;                            // mt*9 + khw
  int khw = r3 % 9;
  int mt  = r3 / 9;
  int jsrc  = jcp ^ (mr & 7);
  int oc    = mt * 128 + mr;
  int cbase = ch * 64 + jsrc * 8;
  u16 o[8];
#pragma unroll
  for (int e = 0; e < 8; ++e)
    o[e] = f2bf(w[(size_t)(oc * CIN + cbase + e) * 9 + khw]);
  uint4 v;
  v.x = (u32)o[0] | ((u32)o[1] << 16);
  v.y = (u32)o[2] | ((u32)o[3] << 16);
  v.z = (u32)o[4] | ((u32)o[5] << 16);
  v.w = (u32)o[6] | ((u32)o[7] << 16);
  *(uint4*)(&wp[(size_t)b * 8]) = v;
}

// ---------------- pre-pass 2: transpose x to channel-last bf16 ----------------
// xp layout: [ch(2)][h(224)][w(224)][jc'(8)][e(8)]; block jc' holds c-block jc'^(w&7)
__global__ void pack_x(const float* __restrict__ x, u16* __restrict__ xp) {
  int h  = blockIdx.x;
  int ch = blockIdx.y;
  __shared__ u16 tile[64][226];                 // [c][w], padded
  int t = threadIdx.x;
#pragma unroll
  for (int i = 0; i < 14; ++i) {                // 64 rows * 56 float4 = 3584
    int idx = i * 256 + t;
    int c   = idx / 56;
    int wq  = idx % 56;
    float4 v = *(const float4*)(&x[(size_t)(ch * 64 + c) * (HH * WW) + h * WW + wq * 4]);
    tile[c][wq * 4 + 0] = f2bf(v.x);
    tile[c][wq * 4 + 1] = f2bf(v.y);
    tile[c][wq * 4 + 2] = f2bf(v.z);
    tile[c][wq * 4 + 3] = f2bf(v.w);
  }
  __syncthreads();
#pragma unroll
  for (int i = 0; i < 7; ++i) {                 // 224 w * 8 blocks = 1792
    int idx  = i * 256 + t;
    int w    = idx >> 3;
    int jcp  = idx & 7;
    int jsrc = jcp ^ (w & 7);
    u16 o[8];
#pragma unroll
    for (int e = 0; e < 8; ++e) o[e] = tile[jsrc * 8 + e][w];
    uint4 v;
    v.x = (u32)o[0] | ((u32)o[1] << 16);
    v.y = (u32)o[2] | ((u32)o[3] << 16);
    v.z = (u32)o[4] | ((u32)o[5] << 16);
    v.w = (u32)o[6] | ((u32)o[7] << 16);
    *(uint4*)(&xp[(size_t)ch * PLANE + (size_t)(h * WW + w) * 64 + jcp * 8]) = v;
  }
}

// ---------------- async global->LDS, 16B per lane (CK-style addrspace cast) ----------------
__device__ __forceinline__ void lds_dma16(const u16* g, u16* l) {
  __builtin_amdgcn_global_load_lds(
      reinterpret_cast<__attribute__((address_space(1))) u32*>(
          reinterpret_cast<uintptr_t>(g)),
      reinterpret_cast<__attribute__((address_space(3))) u32*>(
          reinterpret_cast<uintptr_t>(l)),
      16, 0, 0);
}

// ---------------- main: implicit-GEMM conv, 128x128 tile, bf16 MFMA ----------------
// grid (nb=2, mt=2, oh=222), block 256 (4 waves); wave tile 64x64 as 4x4 of 16x16x32
__global__ __launch_bounds__(256, 3) void conv_mfma(const u16* __restrict__ wp,
                                                    const u16* __restrict__ xp,
                                                    float* __restrict__ out) {
  __shared__ u16 ldsA[128 * 64];   // [m][k64], 16 KB
  __shared__ u16 ldsB[128 * 64];   // [n][k64], 16 KB

  const int tid    = threadIdx.x;
  const int lane   = tid & 63;
  const int wave   = tid >> 6;
  const int quad   = lane >> 4;
  const int lr     = lane & 15;
  const int wave_m = wave >> 1;
  const int wave_n = wave & 1;

  const int nb      = blockIdx.x;     // 0/1
  const int mt      = blockIdx.y;     // 0/1
  const int oh      = blockIdx.z;     // 0..221
  const int ow_base = nb * 94;        // {0, 94}: 34-col overlap, no masking anywhere

  f32x4 acc[4][4];
#pragma unroll
  for (int i = 0; i < 4; ++i)
#pragma unroll
    for (int j = 0; j < 4; ++j) acc[i][j] = {0.f, 0.f, 0.f, 0.f};

  int rowA[4], rowB[4];
#pragma unroll
  for (int i = 0; i < 4; ++i) {
    rowA[i] = (wave_m * 64 + i * 16 + lr) * 64;
    rowB[i] = (wave_n * 64 + i * 16 + lr) * 64;
  }
  const int m7  = lr & 7;
  const int stg = wave * 2048 + lane * 8;   // this lane's first staging elem

  for (int it = 0; it < 18; ++it) {
    const int ch = it & 1;
    const int t2 = it >> 1;                 // kh*3+kw
    const int kw = t2 % 3;
    const int kh = t2 / 3;

    const u16* Ag = wp + (size_t)((mt * 9 + t2) * 2 + ch) * 8192;
    const u16* Bg = xp + (size_t)ch * PLANE +
                    (size_t)((oh + kh) * WW + ow_base + kw) * 64;

    __syncthreads();                        // protect LDS (WAR vs prev iter reads)
#pragma unroll
    for (int i = 0; i < 4; ++i) {
      lds_dma16(Ag + stg + i * 512, &ldsA[wave * 2048 + i * 512]);
      lds_dma16(Bg + stg + i * 512, &ldsB[wave * 2048 + i * 512]);
    }
    __syncthreads();                        // vmcnt(0) drain -> LDS valid

    const int wb7 = (ow_base + kw + lr) & 7;

#pragma unroll
    for (int ks = 0; ks < 2; ++ks) {
      const int jc = ks * 4 + quad;         // 16B k-block index 0..7
      bf16x8 af[4], bg[4];
#pragma unroll
      for (int i = 0; i < 4; ++i)
        af[i] = *reinterpret_cast<const bf16x8*>(&ldsA[rowA[i] + ((jc ^ m7) << 3)]);
#pragma unroll
      for (int i = 0; i < 4; ++i)
        bg[i] = *reinterpret_cast<const bf16x8*>(&ldsB[rowB[i] + ((jc ^ wb7) << 3)]);
#pragma unroll
      for (int i = 0; i < 4; ++i)
#pragma unroll
        for (int j = 0; j < 4; ++j)
          acc[i][j] = __builtin_amdgcn_mfma_f32_16x16x32_bf16(af[i], bg[j], acc[i][j], 0, 0, 0);
    }
  }

  // epilogue: C/D map col=lane&15, row=quad*4+reg (verified m89/m91)
  const int m_base = mt * 128 + wave_m * 64;
  const int n_base = ow_base + wave_n * 64;
#pragma unroll
  for (int i = 0; i < 4; ++i) {
#pragma unroll
    for (int j = 0; j < 4; ++j) {
      float* op = out + (size_t)(m_base + i * 16 + quad * 4) * (HO * WO) +
                  (size_t)oh * WO + (n_base + j * 16 + lr);
#pragma unroll
      for (int r = 0; r < 4; ++r)
        op[(size_t)r * (HO * WO)] = acc[i][j][r];
    }
  }
}

// ---------------- fallback (ws too small): naive fp32 direct conv ----------------
__global__ void conv_naive(const float* __restrict__ x, const float* __restrict__ w,
                           float* __restrict__ out) {
  int idx = blockIdx.x * 256 + threadIdx.x;
  if (idx >= COUT * HO * WO) return;
  int ow  = idx % WO;
  int tmp = idx / WO;
  int oh  = tmp % HO;
  int oc  = tmp / HO;
  float s = 0.f;
  for (int c = 0; c < CIN; ++c)
    for (int kh = 0; kh < 3; ++kh) {
      const float* xr = &x[(size_t)(c * HH + oh + kh) * WW + ow];
      const float* wr = &w[((size_t)(oc * CIN + c) * 3 + kh) * 3];
      s += xr[0] * wr[0] + xr[1] * wr[1] + xr[2] * wr[2];
    }
  out[idx] = s;
}

extern "C" void kernel_launch(void* const* d_in, const int* in_sizes, int n_in,
                              void* d_out, int out_size, void* d_ws, size_t ws_size,
                              hipStream_t stream) {
  const float* x    = (const float*)d_in[0];
  const float* kern = (const float*)d_in[1];
  float* out        = (float*)d_out;

  const size_t WP_BYTES = (size_t)36864 * 16;        // 589,824
  const size_t XP_BYTES = (size_t)2 * PLANE * 2;     // 12,845,056

  if (ws_size >= WP_BYTES + XP_BYTES) {
    u16* wp = (u16*)d_ws;
    u16* xp = (u16*)((char*)d_ws + WP_BYTES);
    hipLaunchKernelGGL(pack_w, dim3(144), dim3(256), 0, stream, kern, wp);
    hipLaunchKernelGGL(pack_x, dim3(224, 2), dim3(256), 0, stream, x, xp);
    hipLaunchKernelGGL(conv_mfma, dim3(2, 2, 222), dim3(256), 0, stream, wp, xp, out);
  } else {
    int total = COUT * HO * WO;
    hipLaunchKernelGGL(conv_naive, dim3((total + 255) / 256), dim3(256), 0, stream,
                       x, kern, out);
  }
}

// Round 2
// 122.729 us; speedup vs baseline: 1.0265x; 1.0265x over previous
//
#include <hip/hip_runtime.h>

#define CIN   128
#define HH    224
#define WW    224
#define COUT  256
#define HO    222
#define WO    222
#define PLANE (224 * 224 * 64)   // one channel-half plane of packed x, in elems

typedef unsigned short u16;
typedef unsigned int   u32;
typedef __bf16  bf16x8 __attribute__((ext_vector_type(8)));
typedef float   f32x4  __attribute__((ext_vector_type(4)));

__device__ __forceinline__ u16 f2bf(float f) {
  union { float f; u32 u; } v; v.f = f;
  u32 u = v.u;
  return (u16)((u + 0x7FFFu + ((u >> 16) & 1u)) >> 16);  // RNE
}

// ---------------- merged pre-pass ----------------
// blocks 0..447: pack x -> xp [ch(2)][h(224)][w(224)][jc'(8)][e(8)] bf16,
//                block jc' holds c-block jc'^(w&7)  (bank/granule swizzle)
// blocks 448..591: pack w -> wp [mt(2)][kh(3)][ch(2)][kw(3)][mr(128)][jc'(8)][e(8)],
//                block jc' holds c-block jc'^(mr&7)
__global__ void prep(const float* __restrict__ x, const float* __restrict__ w,
                     u16* __restrict__ xp, u16* __restrict__ wp) {
  const int t = threadIdx.x;
  if (blockIdx.x < 448) {
    const int h  = blockIdx.x >> 1;
    const int ch = blockIdx.x & 1;
    __shared__ u16 tile[64][228];               // row stride 456B = 57*8 -> b64-aligned
#pragma unroll
    for (int i = 0; i < 14; ++i) {              // 64 c-rows * 56 float4 = 3584 units
      int idx = i * 256 + t;
      int c   = idx / 56;
      int wq  = idx % 56;
      float4 v = *(const float4*)(&x[(size_t)(ch * 64 + c) * (HH * WW) + h * WW + wq * 4]);
      uint2 p;
      p.x = (u32)f2bf(v.x) | ((u32)f2bf(v.y) << 16);
      p.y = (u32)f2bf(v.z) | ((u32)f2bf(v.w) << 16);
      *(uint2*)(&tile[c][wq * 4]) = p;
    }
    __syncthreads();
#pragma unroll
    for (int i = 0; i < 7; ++i) {               // 224 w * 8 blocks = 1792
      int idx  = i * 256 + t;
      int ww   = idx >> 3;
      int jcp  = idx & 7;
      int jsrc = jcp ^ (ww & 7);
      uint4 v;
      v.x = (u32)tile[jsrc * 8 + 0][ww] | ((u32)tile[jsrc * 8 + 1][ww] << 16);
      v.y = (u32)tile[jsrc * 8 + 2][ww] | ((u32)tile[jsrc * 8 + 3][ww] << 16);
      v.z = (u32)tile[jsrc * 8 + 4][ww] | ((u32)tile[jsrc * 8 + 5][ww] << 16);
      v.w = (u32)tile[jsrc * 8 + 6][ww] | ((u32)tile[jsrc * 8 + 7][ww] << 16);
      *(uint4*)(&xp[(size_t)ch * PLANE + (size_t)(h * WW + ww) * 64 + jcp * 8]) = v;
    }
  } else {
    int u    = (blockIdx.x - 448) * 256 + t;    // 0..36863 (16B blocks of wp)
    int jcp  = u & 7;
    int mr   = (u >> 3) & 127;
    int rest = u >> 10;                         // ((mt*3+kh)*2+ch)*3+kw
    int kw   = rest % 3;
    int q    = rest / 3;
    int ch   = q & 1;
    int r    = q >> 1;
    int kh   = r % 3;
    int mt   = r / 3;
    int oc   = mt * 128 + mr;
    int cb   = ch * 64 + (jcp ^ (mr & 7)) * 8;
    u16 o[8];
#pragma unroll
    for (int e = 0; e < 8; ++e)
      o[e] = f2bf(w[((size_t)(oc * CIN + cb + e) * 3 + kh) * 3 + kw]);
    uint4 v;
    v.x = (u32)o[0] | ((u32)o[1] << 16);
    v.y = (u32)o[2] | ((u32)o[3] << 16);
    v.z = (u32)o[4] | ((u32)o[5] << 16);
    v.w = (u32)o[6] | ((u32)o[7] << 16);
    *(uint4*)(&wp[(size_t)u * 8]) = v;
  }
}

// ---------------- async global->LDS, 16B per lane ----------------
__device__ __forceinline__ void lds_dma16(const u16* g, u16* l) {
  __builtin_amdgcn_global_load_lds(
      reinterpret_cast<__attribute__((address_space(1))) u32*>(
          reinterpret_cast<uintptr_t>(g)),
      reinterpret_cast<__attribute__((address_space(3))) u32*>(
          reinterpret_cast<uintptr_t>(l)),
      16, 0, 0);
}

// ---------------- main: full-row implicit-GEMM conv ----------------
// grid (oh=222, mt=2), 256 threads (4 waves). Block tile: M=128, N=224 (full x row).
// B (x row, 28KB) staged in LDS once per (ch,kh) round = 6 stagings / 12 barriers.
// All 3 kw reuse the staged row (reads shift by kw columns). A-fragments load
// directly global->VGPR from L2-resident packed weights (no LDS round-trip).
// Wave tile 64x112 = 4x7 frags of 16x16x32.
__global__ __launch_bounds__(256, 2) void conv_mfma(const u16* __restrict__ wp,
                                                    const u16* __restrict__ xp,
                                                    float* __restrict__ out) {
  __shared__ u16 ldsB[226 * 64];   // rows 224..225 intentionally stale (masked lanes only)

  const int tid  = threadIdx.x;
  const int lane = tid & 63;
  const int wave = tid >> 6;
  const int quad = lane >> 4;
  const int lr   = lane & 15;
  const int wm   = wave >> 1;      // wave m-tile 0/1
  const int wn   = wave & 1;       // wave n-tile 0/1

  const int oh = blockIdx.x;       // 0..221
  const int mt = blockIdx.y;       // 0/1

  f32x4 acc[4][7];
#pragma unroll
  for (int i = 0; i < 4; ++i)
#pragma unroll
    for (int j = 0; j < 7; ++j) acc[i][j] = {0.f, 0.f, 0.f, 0.f};

  int swA[2];
#pragma unroll
  for (int ks = 0; ks < 2; ++ks)
    swA[ks] = ((ks * 4 + quad) ^ (lr & 7)) << 3;

  for (int s = 0; s < 6; ++s) {
    const int ch = s & 1;
    const int kh = s >> 1;

    const u16* g = xp + (size_t)ch * PLANE + (size_t)(oh + kh) * (WW * 64);

    __syncthreads();               // WAR: prev round's B reads done before overwrite
#pragma unroll
    for (int uu = 0; uu < 7; ++uu) {
      const int unit = wave * 7 + uu;          // 28 x 1KB units = full row
      lds_dma16(g + unit * 512 + lane * 8, &ldsB[unit * 512]);
    }
    __syncthreads();               // drain -> LDS valid

    // per-lane A base for this round (wp is L2-resident, reads use full 64B granules)
    const u16* Ab = wp + (size_t)((mt * 3 + kh) * 2 + ch) * 24576 + wm * 4096 + lr * 64;

#pragma unroll
    for (int kw = 0; kw < 3; ++kw) {
      const int bq  = (wn * 112 + lr + kw) * 64;       // j=0 row offset in ldsB
      const int sw7 = (lr + kw) & 7;
#pragma unroll
      for (int ks = 0; ks < 2; ++ks) {
        const int swB = ((ks * 4 + quad) ^ sw7) << 3;
        bf16x8 af[4], bg[7];
#pragma unroll
        for (int i = 0; i < 4; ++i)
          af[i] = *reinterpret_cast<const bf16x8*>(Ab + kw * 8192 + i * 1024 + swA[ks]);
#pragma unroll
        for (int j = 0; j < 7; ++j)
          bg[j] = *reinterpret_cast<const bf16x8*>(&ldsB[bq + j * 1024 + swB]);
#pragma unroll
        for (int i = 0; i < 4; ++i)
#pragma unroll
          for (int j = 0; j < 7; ++j)
            acc[i][j] = __builtin_amdgcn_mfma_f32_16x16x32_bf16(af[i], bg[j], acc[i][j], 0, 0, 0);
      }
    }
  }

  // epilogue: C/D map col=lane&15, row=quad*4+reg (m89/m91); mask cols 222/223
  const int mb = mt * 128 + wm * 64;
#pragma unroll
  for (int i = 0; i < 4; ++i) {
#pragma unroll
    for (int j = 0; j < 7; ++j) {
      const int col = wn * 112 + j * 16 + lr;
      if (col < WO) {
        float* op = out + (size_t)(mb + i * 16 + quad * 4) * (HO * WO) +
                    (size_t)oh * WO + col;
#pragma unroll
        for (int r = 0; r < 4; ++r)
          op[(size_t)r * (HO * WO)] = acc[i][j][r];
      }
    }
  }
}

// ---------------- fallback (ws too small): naive fp32 direct conv ----------------
__global__ void conv_naive(const float* __restrict__ x, const float* __restrict__ w,
                           float* __restrict__ out) {
  int idx = blockIdx.x * 256 + threadIdx.x;
  if (idx >= COUT * HO * WO) return;
  int ow  = idx % WO;
  int tmp = idx / WO;
  int oh  = tmp % HO;
  int oc  = tmp / HO;
  float s = 0.f;
  for (int c = 0; c < CIN; ++c)
    for (int kh = 0; kh < 3; ++kh) {
      const float* xr = &x[(size_t)(c * HH + oh + kh) * WW + ow];
      const float* wr = &w[((size_t)(oc * CIN + c) * 3 + kh) * 3];
      s += xr[0] * wr[0] + xr[1] * wr[1] + xr[2] * wr[2];
    }
  out[idx] = s;
}

extern "C" void kernel_launch(void* const* d_in, const int* in_sizes, int n_in,
                              void* d_out, int out_size, void* d_ws, size_t ws_size,
                              hipStream_t stream) {
  const float* x    = (const float*)d_in[0];
  const float* kern = (const float*)d_in[1];
  float* out        = (float*)d_out;

  const size_t WP_BYTES = (size_t)36864 * 16;        // 589,824
  const size_t XP_BYTES = (size_t)2 * PLANE * 2;     // 12,845,056

  if (ws_size >= WP_BYTES + XP_BYTES) {
    u16* wp = (u16*)d_ws;
    u16* xp = (u16*)((char*)d_ws + WP_BYTES);
    hipLaunchKernelGGL(prep, dim3(592), dim3(256), 0, stream, x, kern, xp, wp);
    hipLaunchKernelGGL(conv_mfma, dim3(222, 2), dim3(256), 0, stream, wp, xp, out);
  } else {
    int total = COUT * HO * WO;
    hipLaunchKernelGGL(conv_naive, dim3((total + 255) / 256), dim3(256), 0, stream,
                       x, kern, out);
  }
}

// Round 3
// 116.991 us; speedup vs baseline: 1.0768x; 1.0490x over previous
//
#include <hip/hip_runtime.h>

#define CIN   128
#define HH    224
#define WW    224
#define COUT  256
#define HO    222
#define WO    222
#define PLANE (224 * 224 * 64)   // one channel-half plane of packed x, in elems

typedef unsigned short u16;
typedef unsigned int   u32;
typedef __bf16  bf16x8 __attribute__((ext_vector_type(8)));
typedef float   f32x4  __attribute__((ext_vector_type(4)));

__device__ __forceinline__ u16 f2bf(float f) {
  union { float f; u32 u; } v; v.f = f;
  u32 u = v.u;
  return (u16)((u + 0x7FFFu + ((u >> 16) & 1u)) >> 16);  // RNE
}

// ---------------- merged pre-pass ----------------
// blocks 0..447: pack x -> xp [ch(2)][h(224)][w(224)][jc'(8)][e(8)] bf16,
//                block jc' holds c-block jc'^(w&7)  (bank/granule swizzle)
// blocks 448..591: pack w -> wp [mt(2)][kh(3)][ch(2)][kw(3)][mr(128)][jc'(8)][e(8)],
//                block jc' holds c-block jc'^(mr&7)
__global__ void prep(const float* __restrict__ x, const float* __restrict__ w,
                     u16* __restrict__ xp, u16* __restrict__ wp) {
  const int t = threadIdx.x;
  if (blockIdx.x < 448) {
    const int h  = blockIdx.x >> 1;
    const int ch = blockIdx.x & 1;
    __shared__ u16 tile[64][228];               // row stride 456B = 57*8 -> b64-aligned
#pragma unroll
    for (int i = 0; i < 14; ++i) {              // 64 c-rows * 56 float4 = 3584 units
      int idx = i * 256 + t;
      int c   = idx / 56;
      int wq  = idx % 56;
      float4 v = *(const float4*)(&x[(size_t)(ch * 64 + c) * (HH * WW) + h * WW + wq * 4]);
      uint2 p;
      p.x = (u32)f2bf(v.x) | ((u32)f2bf(v.y) << 16);
      p.y = (u32)f2bf(v.z) | ((u32)f2bf(v.w) << 16);
      *(uint2*)(&tile[c][wq * 4]) = p;
    }
    __syncthreads();
#pragma unroll
    for (int i = 0; i < 7; ++i) {               // 224 w * 8 blocks = 1792
      int idx  = i * 256 + t;
      int ww   = idx >> 3;
      int jcp  = idx & 7;
      int jsrc = jcp ^ (ww & 7);
      uint4 v;
      v.x = (u32)tile[jsrc * 8 + 0][ww] | ((u32)tile[jsrc * 8 + 1][ww] << 16);
      v.y = (u32)tile[jsrc * 8 + 2][ww] | ((u32)tile[jsrc * 8 + 3][ww] << 16);
      v.z = (u32)tile[jsrc * 8 + 4][ww] | ((u32)tile[jsrc * 8 + 5][ww] << 16);
      v.w = (u32)tile[jsrc * 8 + 6][ww] | ((u32)tile[jsrc * 8 + 7][ww] << 16);
      *(uint4*)(&xp[(size_t)ch * PLANE + (size_t)(h * WW + ww) * 64 + jcp * 8]) = v;
    }
  } else {
    int u    = (blockIdx.x - 448) * 256 + t;    // 0..36863 (16B blocks of wp)
    int jcp  = u & 7;
    int mr   = (u >> 3) & 127;
    int rest = u >> 10;                         // ((mt*3+kh)*2+ch)*3+kw
    int kw   = rest % 3;
    int q    = rest / 3;
    int ch   = q & 1;
    int r    = q >> 1;
    int kh   = r % 3;
    int mt   = r / 3;
    int oc   = mt * 128 + mr;
    int cb   = ch * 64 + (jcp ^ (mr & 7)) * 8;
    u16 o[8];
#pragma unroll
    for (int e = 0; e < 8; ++e)
      o[e] = f2bf(w[((size_t)(oc * CIN + cb + e) * 3 + kh) * 3 + kw]);
    uint4 v;
    v.x = (u32)o[0] | ((u32)o[1] << 16);
    v.y = (u32)o[2] | ((u32)o[3] << 16);
    v.z = (u32)o[4] | ((u32)o[5] << 16);
    v.w = (u32)o[6] | ((u32)o[7] << 16);
    *(uint4*)(&wp[(size_t)u * 8]) = v;
  }
}

// ---------------- async global->LDS, 16B per lane ----------------
__device__ __forceinline__ void lds_dma16(const u16* g, u16* l) {
  __builtin_amdgcn_global_load_lds(
      reinterpret_cast<__attribute__((address_space(1))) u32*>(
          reinterpret_cast<uintptr_t>(g)),
      reinterpret_cast<__attribute__((address_space(3))) u32*>(
          reinterpret_cast<uintptr_t>(l)),
      16, 0, 0);
}

// ---------------- main: full-row implicit-GEMM conv, XCD-banded ----------------
// grid 448 blocks, 1D. Workgroup dispatch round-robins XCDs, so xcd = bx & 7.
// Remap so each XCD owns a contiguous band of 28 output rows (both mt halves):
//   bx = oh_local*16 + mt*8 + xcd  ->  oh = xcd*28 + oh_local.
// Per-XCD working set: 30 xp rows (57KB each, both ch) + wp = ~2.3MB < 4MB L2,
// so staging DMAs become L2 hits instead of cross-XCD-duplicated HBM misses.
// Block tile: M=128, N=224 (full row). B staged in LDS once per (ch,kh) = 6
// rounds; all 3 kw reuse the staged row. A-frags load global->VGPR from
// L2-resident packed weights. Wave tile 64x112 = 4x7 frags of 16x16x32.
__global__ __launch_bounds__(256, 2) void conv_mfma(const u16* __restrict__ wp,
                                                    const u16* __restrict__ xp,
                                                    float* __restrict__ out) {
  __shared__ u16 ldsB[226 * 64];   // rows 224..225 stale (read only by masked cols)

  const int tid  = threadIdx.x;
  const int lane = tid & 63;
  const int wave = tid >> 6;
  const int quad = lane >> 4;
  const int lr   = lane & 15;
  const int wm   = wave >> 1;      // wave m-tile 0/1
  const int wn   = wave & 1;       // wave n-tile 0/1

  const int bx  = blockIdx.x;
  const int xcd = bx & 7;
  const int mt  = (bx >> 3) & 1;
  const int oh  = xcd * 28 + (bx >> 4);   // 0..223
  if (oh >= HO) return;                    // 4 blocks idle (wave-uniform exit)

  f32x4 acc[4][7];
#pragma unroll
  for (int i = 0; i < 4; ++i)
#pragma unroll
    for (int j = 0; j < 7; ++j) acc[i][j] = {0.f, 0.f, 0.f, 0.f};

  int swA[2];
#pragma unroll
  for (int ks = 0; ks < 2; ++ks)
    swA[ks] = ((ks * 4 + quad) ^ (lr & 7)) << 3;

  for (int s = 0; s < 6; ++s) {
    const int ch = s & 1;
    const int kh = s >> 1;

    const u16* g = xp + (size_t)ch * PLANE + (size_t)(oh + kh) * (WW * 64);

    __syncthreads();               // WAR: prev round's B reads done before overwrite
#pragma unroll
    for (int uu = 0; uu < 7; ++uu) {
      const int unit = wave * 7 + uu;          // 28 x 1KB units = full row
      lds_dma16(g + unit * 512 + lane * 8, &ldsB[unit * 512]);
    }
    __syncthreads();               // drain -> LDS valid

    // per-lane A base for this round (wp L2-resident; frag reads hit 64B granules)
    const u16* Ab = wp + (size_t)((mt * 3 + kh) * 2 + ch) * 24576 + wm * 4096 + lr * 64;

#pragma unroll
    for (int kw = 0; kw < 3; ++kw) {
      const int bq  = (wn * 112 + lr + kw) * 64;       // j=0 row offset in ldsB
      const int sw7 = (lr + kw) & 7;
#pragma unroll
      for (int ks = 0; ks < 2; ++ks) {
        const int swB = ((ks * 4 + quad) ^ sw7) << 3;
        bf16x8 af[4], bg[7];
#pragma unroll
        for (int i = 0; i < 4; ++i)
          af[i] = *reinterpret_cast<const bf16x8*>(Ab + kw * 8192 + i * 1024 + swA[ks]);
#pragma unroll
        for (int j = 0; j < 7; ++j)
          bg[j] = *reinterpret_cast<const bf16x8*>(&ldsB[bq + j * 1024 + swB]);
#pragma unroll
        for (int i = 0; i < 4; ++i)
#pragma unroll
          for (int j = 0; j < 7; ++j)
            acc[i][j] = __builtin_amdgcn_mfma_f32_16x16x32_bf16(af[i], bg[j], acc[i][j], 0, 0, 0);
      }
    }
  }

  // epilogue: C/D map col=lane&15, row=quad*4+reg (m89/m91); mask cols 222/223
  const int mb = mt * 128 + wm * 64;
#pragma unroll
  for (int i = 0; i < 4; ++i) {
#pragma unroll
    for (int j = 0; j < 7; ++j) {
      const int col = wn * 112 + j * 16 + lr;
      if (col < WO) {
        float* op = out + (size_t)(mb + i * 16 + quad * 4) * (HO * WO) +
                    (size_t)oh * WO + col;
#pragma unroll
        for (int r = 0; r < 4; ++r)
          op[(size_t)r * (HO * WO)] = acc[i][j][r];
      }
    }
  }
}

// ---------------- fallback (ws too small): naive fp32 direct conv ----------------
__global__ void conv_naive(const float* __restrict__ x, const float* __restrict__ w,
                           float* __restrict__ out) {
  int idx = blockIdx.x * 256 + threadIdx.x;
  if (idx >= COUT * HO * WO) return;
  int ow  = idx % WO;
  int tmp = idx / WO;
  int oh  = tmp % HO;
  int oc  = tmp / HO;
  float s = 0.f;
  for (int c = 0; c < CIN; ++c)
    for (int kh = 0; kh < 3; ++kh) {
      const float* xr = &x[(size_t)(c * HH + oh + kh) * WW + ow];
      const float* wr = &w[((size_t)(oc * CIN + c) * 3 + kh) * 3];
      s += xr[0] * wr[0] + xr[1] * wr[1] + xr[2] * wr[2];
    }
  out[idx] = s;
}

extern "C" void kernel_launch(void* const* d_in, const int* in_sizes, int n_in,
                              void* d_out, int out_size, void* d_ws, size_t ws_size,
                              hipStream_t stream) {
  const float* x    = (const float*)d_in[0];
  const float* kern = (const float*)d_in[1];
  float* out        = (float*)d_out;

  const size_t WP_BYTES = (size_t)36864 * 16;        // 589,824
  const size_t XP_BYTES = (size_t)2 * PLANE * 2;     // 12,845,056

  if (ws_size >= WP_BYTES + XP_BYTES) {
    u16* wp = (u16*)d_ws;
    u16* xp = (u16*)((char*)d_ws + WP_BYTES);
    hipLaunchKernelGGL(prep, dim3(592), dim3(256), 0, stream, x, kern, xp, wp);
    hipLaunchKernelGGL(conv_mfma, dim3(448), dim3(256), 0, stream, wp, xp, out);
  } else {
    int total = COUT * HO * WO;
    hipLaunchKernelGGL(conv_naive, dim3((total + 255) / 256), dim3(256), 0, stream,
                       x, kern, out);
  }
}